// Round 5
// baseline (283.317 us; speedup 1.0000x reference)
//
#include <hip/hip_runtime.h>
#include <math.h>

#define F 128
#define DEG 5
#define TN 128
#define MAXNORM_D 0.996          // (1 - 4e-3)/sqrt(c), c=1
#define MIN_NORM_D 1e-15

__device__ inline double atanh_clip(double v) {
    v = fmin(fmax(v, -1.0 + 1e-7), 1.0 - 1e-7);
    return atanh(v);
}

__device__ inline void load_lds16(const void* g, void* l) {
    __builtin_amdgcn_global_load_lds((const __attribute__((address_space(1))) void*)g,
                                     (__attribute__((address_space(3))) void*)l, 16, 0, 0);
}

// ---------------------------------------------------------------- K0: WT[k][f] = W[f][k] (once, 64 KB)
__global__ __launch_bounds__(256) void k_wt(const float* __restrict__ W, float* __restrict__ WT) {
    int t = blockIdx.x * 256 + threadIdx.x;   // 4096 threads, one float4 of W each
    int f = t >> 5;
    int k4 = (t & 31) * 4;
    float4 w = *(const float4*)&W[f * F + k4];
    WT[(k4 + 0) * F + f] = w.x;
    WT[(k4 + 1) * F + f] = w.y;
    WT[(k4 + 2) * F + f] = w.z;
    WT[(k4 + 3) * F + f] = w.w;
}

// ---------------------------------------------------------------- K1: in-degree histogram of dst
__global__ __launch_bounds__(256) void k_hist(const int* __restrict__ edge, int* __restrict__ cnt, int E) {
    int e = blockIdx.x * 256 + threadIdx.x;
    if (e < E) atomicAdd(&cnt[edge[E + e]], 1);
}

// ---------------------------------------------------------------- K2: y = x @ W^T  [N,128]
// Single-barrier structure: full pre-transposed W (64 KB) staged ONCE via
// global_load_lds; X read straight from global in its natural layout (float4,
// lane-broadcast, L1-served) with a 1-deep software pipeline. 8f x 8n
// microtile per thread, TN=128 nodes/block.
// Fused: ssum2[f] += sum_n y[n,f]^2 ; wsum2[f] += sum_n cnt[n]*y[n,f]^2
__global__ __launch_bounds__(256) void k_gemm(const float* __restrict__ x, const float* __restrict__ WT,
                                              const int* __restrict__ cnt, float* __restrict__ y,
                                              float* __restrict__ ssum2, float* __restrict__ wsum2, int N) {
    __shared__ float Ws[F * F];     // [k][f]  64 KB
    __shared__ float red_ss[F];
    __shared__ float red_ws[F];
    __shared__ int cntL[TN];

    int t = threadIdx.x;
    int n0 = blockIdx.x * TN;
    int lane = t & 63;
    int wv = t >> 6;

    // stage all of WT: contiguous 64 KB, wave-uniform base + lane*16
    {
        const char* src = (const char*)WT;
        char* dst = (char*)Ws;
#pragma unroll
        for (int r = 0; r < 16; r++) {
            int off = wv * 16384 + r * 1024 + lane * 16;
            load_lds16(src + off, dst + off);
        }
    }
    if (t < F) { red_ss[t] = 0.f; red_ws[t] = 0.f; }
    if (t < TN) { int n = n0 + t; cntL[t] = (n < N) ? cnt[n] : 0; }

    int f0 = (t & 15) * 8;       // 8 consecutive f
    int nb = (t >> 4) * 8;       // 8 consecutive local n

    const float* xr[8];
#pragma unroll
    for (int j = 0; j < 8; j++) {
        int rn = n0 + nb + j; if (rn > N - 1) rn = N - 1;   // clamp: safe, masked later
        xr[j] = x + (size_t)rn * F;
    }

    float4 accA[8], accB[8];
#pragma unroll
    for (int j = 0; j < 8; j++) {
        accA[j] = make_float4(0.f, 0.f, 0.f, 0.f);
        accB[j] = make_float4(0.f, 0.f, 0.f, 0.f);
    }

    float4 xv[8], xn[8];
#pragma unroll
    for (int j = 0; j < 8; j++) xv[j] = *(const float4*)(xr[j]);   // k4 = 0

    __syncthreads();   // Ws ready (single barrier drain in whole kernel)

#define FMA_BLOCK(K4)                                                          \
    {                                                                          \
        _Pragma("unroll")                                                      \
        for (int kk = 0; kk < 4; kk++) {                                       \
            float4 wA = *(const float4*)&Ws[((K4) + kk) * F + f0];             \
            float4 wB = *(const float4*)&Ws[((K4) + kk) * F + f0 + 4];         \
            _Pragma("unroll")                                                  \
            for (int j = 0; j < 8; j++) {                                      \
                float s = kk == 0 ? xv[j].x : kk == 1 ? xv[j].y                \
                        : kk == 2 ? xv[j].z : xv[j].w;                         \
                accA[j].x = fmaf(s, wA.x, accA[j].x);                          \
                accA[j].y = fmaf(s, wA.y, accA[j].y);                          \
                accA[j].z = fmaf(s, wA.z, accA[j].z);                          \
                accA[j].w = fmaf(s, wA.w, accA[j].w);                          \
                accB[j].x = fmaf(s, wB.x, accB[j].x);                          \
                accB[j].y = fmaf(s, wB.y, accB[j].y);                          \
                accB[j].z = fmaf(s, wB.z, accB[j].z);                          \
                accB[j].w = fmaf(s, wB.w, accB[j].w);                          \
            }                                                                  \
        }                                                                      \
    }

    for (int k4 = 0; k4 < F - 4; k4 += 4) {
#pragma unroll
        for (int j = 0; j < 8; j++) xn[j] = *(const float4*)(xr[j] + k4 + 4);  // prefetch
        FMA_BLOCK(k4)
#pragma unroll
        for (int j = 0; j < 8; j++) xv[j] = xn[j];
    }
    FMA_BLOCK(F - 4)
#undef FMA_BLOCK

    // store y (two float4 per row; threads sharing nb cover contiguous f)
#pragma unroll
    for (int j = 0; j < 8; j++) {
        int n = n0 + nb + j;
        if (n < N) {
            *(float4*)&y[(size_t)n * F + f0] = accA[j];
            *(float4*)&y[(size_t)n * F + f0 + 4] = accB[j];
        }
    }
    // fused column sums of squares
    float ssv[8] = {0.f, 0.f, 0.f, 0.f, 0.f, 0.f, 0.f, 0.f};
    float wsv[8] = {0.f, 0.f, 0.f, 0.f, 0.f, 0.f, 0.f, 0.f};
#pragma unroll
    for (int j = 0; j < 8; j++) {
        float valid = (n0 + nb + j < N) ? 1.f : 0.f;   // OOB rows hold clamped garbage
        float c = (float)cntL[nb + j];
        float4 vA = accA[j], vB = accB[j];
        ssv[0] += valid * vA.x * vA.x; ssv[1] += valid * vA.y * vA.y;
        ssv[2] += valid * vA.z * vA.z; ssv[3] += valid * vA.w * vA.w;
        ssv[4] += valid * vB.x * vB.x; ssv[5] += valid * vB.y * vB.y;
        ssv[6] += valid * vB.z * vB.z; ssv[7] += valid * vB.w * vB.w;
        wsv[0] += c * vA.x * vA.x; wsv[1] += c * vA.y * vA.y;
        wsv[2] += c * vA.z * vA.z; wsv[3] += c * vA.w * vA.w;
        wsv[4] += c * vB.x * vB.x; wsv[5] += c * vB.y * vB.y;
        wsv[6] += c * vB.z * vB.z; wsv[7] += c * vB.w * vB.w;
    }
#pragma unroll
    for (int i = 0; i < 8; i++) {
        atomicAdd(&red_ss[f0 + i], ssv[i]);
        atomicAdd(&red_ws[f0 + i], wsv[i]);
    }
    __syncthreads();
    if (t < F) {
        atomicAdd(&ssum2[t], red_ss[t]);
        atomicAdd(&wsum2[t], red_ws[t]);
    }
}

// ---------------------------------------------------------------- K2b: all global scalar factors (f64)
__global__ __launch_bounds__(256) void k_scalars(const float* __restrict__ W, const float* __restrict__ a,
                                                 const float* __restrict__ ssum2, const float* __restrict__ wsum2,
                                                 float* __restrict__ s_arr, float* __restrict__ asrc,
                                                 float* __restrict__ adst, double* __restrict__ an_out) {
    int t = threadIdx.x;
    double av = (double)a[t];
    av *= av;
#pragma unroll
    for (int off = 32; off; off >>= 1) av += __shfl_down(av, off, 64);
    __shared__ double wred[4];
    if ((t & 63) == 0) wred[t >> 6] = av;
    __syncthreads();
    double an = fmax(sqrt(wred[0] + wred[1] + wred[2] + wred[3]), MIN_NORM_D);
    if (t == 0) an_out[0] = an;

    if (t < F) {
        double wn2 = 0.0;
        for (int k = 0; k < F; k++) { double w = (double)W[t * F + k]; wn2 += w * w; }
        double wn = fmax(sqrt(wn2), MIN_NORM_D);
        double mxnf = fmax(sqrt((double)ssum2[t]), MIN_NORM_D);
        double tt = tanh(mxnf / wn * atanh_clip(wn));
        double rn = fmax(tt, MIN_NORM_D);
        double pf = (rn > MAXNORM_D) ? MAXNORM_D / rn : 1.0;
        double pn = rn * pf;
        double s = (tt / mxnf) * pf * atanh_clip(pn) / pn;
        s_arr[t] = (float)s;

        double un_s = fmax(s * sqrt((double)DEG * (double)ssum2[t]), MIN_NORM_D);
        double th_s = tanh(un_s);
        double rn2 = fmax(th_s, MIN_NORM_D);
        double pf2 = (rn2 > MAXNORM_D) ? MAXNORM_D / rn2 : 1.0;
        double q_s = s * (th_s / un_s) * pf2;
        asrc[t] = (float)((double)a[t] * q_s);

        double un_d = fmax(s * sqrt((double)wsum2[t]), MIN_NORM_D);
        double th_d = tanh(un_d);
        double rn3 = fmax(th_d, MIN_NORM_D);
        double pf3 = (rn3 > MAXNORM_D) ? MAXNORM_D / rn3 : 1.0;
        double q_d = s * (th_d / un_d) * pf3;
        adst[t] = (float)((double)a[F + t] * q_d);
    }
}

// ---------------------------------------------------------------- K3: P[n]=dot(asrc,y[n,:]) Q[n]=dot(adst,y[n,:])
__global__ __launch_bounds__(256) void k_pq(const float* __restrict__ y, const float* __restrict__ asrc,
                                            const float* __restrict__ adst, float* __restrict__ P,
                                            float* __restrict__ Q, int N) {
    __shared__ float as4[F], ad4[F];
    int t = threadIdx.x;
    if (t < F) { as4[t] = asrc[t]; ad4[t] = adst[t]; }
    __syncthreads();
    int lane = t & 31;
    int n = blockIdx.x * 8 + (t >> 5);
    if (n < N) {
        float4 yv = *(const float4*)&y[(size_t)n * F + lane * 4];
        float4 av = *(const float4*)&as4[lane * 4];
        float4 bv = *(const float4*)&ad4[lane * 4];
        float p = yv.x * av.x + yv.y * av.y + yv.z * av.z + yv.w * av.w;
        float q = yv.x * bv.x + yv.y * bv.y + yv.z * bv.z + yv.w * bv.w;
#pragma unroll
        for (int off = 16; off; off >>= 1) {
            p += __shfl_down(p, off, 32);
            q += __shfl_down(q, off, 32);
        }
        if (lane == 0) { P[n] = p; Q[n] = q; }
    }
}

// ---------------------------------------------------------------- K4: ee_pre[e] = P[src]+Q[dst]; ||ee_pre||^2 (f64)
__global__ __launch_bounds__(256) void k_edge(const int* __restrict__ edge, const float* __restrict__ P,
                                              const float* __restrict__ Q, float* __restrict__ ee_pre,
                                              double* __restrict__ mxn2, int E) {
    int t = threadIdx.x;
    int e = blockIdx.x * 256 + t;
    double local = 0.0;
    if (e < E) {
        int s = edge[e];
        int d = edge[E + e];
        float v = P[s] + Q[d];
        ee_pre[e] = v;
        local = (double)v * (double)v;
    }
#pragma unroll
    for (int off = 32; off; off >>= 1) local += __shfl_down(local, off, 64);
    __shared__ double wsum[4];
    if ((t & 63) == 0) wsum[t >> 6] = local;
    __syncthreads();
    if (t == 0) atomicAdd(mxn2, wsum[0] + wsum[1] + wsum[2] + wsum[3]);
}

// ---------------------------------------------------------------- K5: per-node NORMALIZED edge weights
__global__ __launch_bounds__(256) void k_w(const float* __restrict__ ee_pre,
                                           const double* __restrict__ an_p, const double* __restrict__ mxn2_p,
                                           float* __restrict__ wn, int N) {
    __shared__ float gS;
    if (threadIdx.x == 0) {
        double an = an_p[0];
        double mxn = fmax(sqrt(mxn2_p[0]), MIN_NORM_D);
        double t2 = tanh(mxn / an * atanh_clip(an));
        double f2 = t2 / mxn;
        double rnp = fmax(t2, MIN_NORM_D);
        double pfp = (rnp > MAXNORM_D) ? MAXNORM_D / rnp : 1.0;
        double pnp = rnp * pfp;
        gS = (float)(f2 * pfp * atanh_clip(pnp) / pnp);
    }
    __syncthreads();
    float g = gS;
    int n = blockIdx.x * 256 + threadIdx.x;
    if (n < N) {
        float r[DEG];
        float rowsum = 0.f;
#pragma unroll
        for (int j = 0; j < DEG; j++) {
            float xg = g * ee_pre[n * DEG + j];
            float gl = 0.5f * xg * (1.f + erff(xg * 0.70710678f));
            float w = expf(-gl);
            r[j] = w;
            rowsum += w;
        }
        float inv = 1.f / rowsum;
#pragma unroll
        for (int j = 0; j < DEG; j++) wn[n * DEG + j] = r[j] * inv;
    }
}

// ---------------------------------------------------------------- K6: per-node aggregate + epilogue
__global__ __launch_bounds__(256) void k_agg(const int* __restrict__ edge, const float* __restrict__ y,
                                             const float* __restrict__ wn, const float* __restrict__ s_arr,
                                             float* __restrict__ out, int N, int E) {
    __shared__ float wsh[8 * DEG];
    __shared__ int dsh[8 * DEG];
    int t = threadIdx.x;
    int n_base = blockIdx.x * 8;

    if (t < 8 * DEG) {
        int n = n_base + t / DEG;
        float w = 0.f; int d = 0;
        if (n < N) {
            int e = n * DEG + (t % DEG);
            w = wn[e];
            d = edge[E + e];
        }
        wsh[t] = w;
        dsh[t] = d << 7;
    }
    __syncthreads();

    int grp = t >> 5;        // 0..7
    int lane = t & 31;
    int n = n_base + grp;
    if (n >= N) return;

    int fo = lane * 4;
    float4 acc = make_float4(0.f, 0.f, 0.f, 0.f);
#pragma unroll
    for (int j = 0; j < DEG; j++) {
        float w = wsh[grp * DEG + j];
        int d = dsh[grp * DEG + j];
        float4 yv = *(const float4*)&y[d + fo];
        acc.x = fmaf(w, yv.x, acc.x);
        acc.y = fmaf(w, yv.y, acc.y);
        acc.z = fmaf(w, yv.z, acc.z);
        acc.w = fmaf(w, yv.w, acc.w);
    }
    float4 s4 = *(const float4*)&s_arr[fo];
    float4 el;
    float hx = s4.x * acc.x; el.x = (hx > 0.f) ? hx : expm1f(hx);
    float hy = s4.y * acc.y; el.y = (hy > 0.f) ? hy : expm1f(hy);
    float hz = s4.z * acc.z; el.z = (hz > 0.f) ? hz : expm1f(hz);
    float hw = s4.w * acc.w; el.w = (hw > 0.f) ? hw : expm1f(hw);

    float ss = el.x * el.x + el.y * el.y + el.z * el.z + el.w * el.w;
#pragma unroll
    for (int off = 16; off; off >>= 1) ss += __shfl_xor(ss, off, 32);

    float un = fmaxf(sqrtf(ss), 1e-15f);
    float th = tanhf(un);
    float sc = th / un;                   // expmap0
    float rn = fmaxf(th, 1e-15f);
    if (rn > 0.996f) sc *= 0.996f / rn;   // proj
    float4 o = make_float4(el.x * sc, el.y * sc, el.z * sc, el.w * sc);
    *(float4*)&out[(size_t)n * F + fo] = o;
}

extern "C" void kernel_launch(void* const* d_in, const int* in_sizes, int n_in,
                              void* d_out, int out_size, void* d_ws, size_t ws_size,
                              hipStream_t stream) {
    const float* x = (const float*)d_in[0];
    const int* edge = (const int*)d_in[1];
    const float* W = (const float*)d_in[2];
    const float* a = (const float*)d_in[3];
    float* out = (float*)d_out;
    int N = in_sizes[0] / F;
    int E = in_sizes[1] / 2;

    char* ws = (char*)d_ws;
    size_t off = 0;
    float* y = (float*)(ws + off);       off += (size_t)N * F * 4;
    float* WT = (float*)(ws + off);      off += (size_t)F * F * 4;   // 16B-aligned
    float* ee_pre = (float*)(ws + off);  off += (size_t)E * 4;
    float* wn = (float*)(ws + off);      off += (size_t)E * 4;
    float* P = (float*)(ws + off);       off += (size_t)N * 4;
    float* Q = (float*)(ws + off);       off += (size_t)N * 4;
    char* zbase = ws + off;
    int* cnt = (int*)(ws + off);         off += (size_t)N * 4;
    float* ssum2 = (float*)(ws + off);   off += 512;
    float* wsum2 = (float*)(ws + off);   off += 512;
    double* mxn2 = (double*)(ws + off);  off += 8;
    size_t zlen = (size_t)((ws + off) - zbase);
    double* an_p = (double*)(ws + off);  off += 8;
    float* s_arr = (float*)(ws + off);   off += 512;
    float* asrc = (float*)(ws + off);    off += 512;
    float* adst = (float*)(ws + off);    off += 512;

    hipMemsetAsync(zbase, 0, zlen, stream);
    k_wt<<<16, 256, 0, stream>>>(W, WT);
    k_hist<<<(E + 255) / 256, 256, 0, stream>>>(edge, cnt, E);
    k_gemm<<<(N + TN - 1) / TN, 256, 0, stream>>>(x, WT, cnt, y, ssum2, wsum2, N);
    k_scalars<<<1, 256, 0, stream>>>(W, a, ssum2, wsum2, s_arr, asrc, adst, an_p);
    k_pq<<<(N + 7) / 8, 256, 0, stream>>>(y, asrc, adst, P, Q, N);
    k_edge<<<(E + 255) / 256, 256, 0, stream>>>(edge, P, Q, ee_pre, mxn2, E);
    k_w<<<(N + 255) / 256, 256, 0, stream>>>(ee_pre, an_p, mxn2, wn, N);
    k_agg<<<(N + 7) / 8, 256, 0, stream>>>(edge, y, wn, s_arr, out, N, E);
}